// Round 3
// baseline (254.046 us; speedup 1.0000x reference)
//
#include <hip/hip_runtime.h>
#include <math.h>

#define ZDIM 128
#define HDIM 100

// Prep: transpose w1 [100][128] -> w1t [128][100] and w3 [9][100] -> w3t [100][9]
// so the main kernel's inner unrolled-j loops read contiguous (wave-uniform) rows.
__global__ void prep_transpose(const float* __restrict__ w1,
                               const float* __restrict__ w3,
                               float* __restrict__ w1t,
                               float* __restrict__ w3t) {
    int idx = blockIdx.x * blockDim.x + threadIdx.x;
    if (idx < HDIM * ZDIM) {
        int j = idx / ZDIM;          // 0..99
        int k = idx - j * ZDIM;      // 0..127
        w1t[k * HDIM + j] = w1[idx];
    }
    if (idx < 9 * HDIM) {
        int r = idx / HDIM;          // 0..8
        int i = idx - r * HDIM;      // 0..99
        w3t[i * 9 + r] = w3[idx];
    }
}

// One thread = one sample.
// Layer 1: k-outer (x streamed as float4), h1[100] in VGPRs (static indices only).
// Layers 2+3 fused: i-outer; tanh(h2[i]) immediately accumulated into m[9].
// Epilogue: scaled Newton polar iteration (fp64) -> nearest orthogonal R = U V^T.
template<bool TR>
__global__ __launch_bounds__(256) void pose_main(
    const float* __restrict__ x,
    const float* __restrict__ w1,   // [100][128]
    const float* __restrict__ b1,   // [100]
    const float* __restrict__ w2,   // [100][100]
    const float* __restrict__ b2,   // [100]
    const float* __restrict__ w3,   // [9][100]
    const float* __restrict__ b3,   // [9]
    const float* __restrict__ w1t,  // [128][100] (TR path)
    const float* __restrict__ w3t,  // [100][9]   (TR path)
    float* __restrict__ out,
    int nB)
{
    int tid = blockIdx.x * blockDim.x + threadIdx.x;
    if (tid >= nB) return;

    const float4* xrow = reinterpret_cast<const float4*>(x + (size_t)tid * ZDIM);

    // ---------- Layer 1: h1 = relu(x @ w1^T + b1) ----------
    float h1[HDIM];
    #pragma unroll
    for (int j = 0; j < HDIM; ++j) h1[j] = b1[j];

    #pragma unroll 1
    for (int k4 = 0; k4 < ZDIM / 4; ++k4) {
        const float4 xk = xrow[k4];
        #pragma unroll
        for (int j = 0; j < HDIM; ++j) {
            float wa, wb, wc, wd;
            if (TR) {
                const float* base = w1t + (size_t)(k4 * 4) * HDIM + j;
                wa = base[0 * HDIM];
                wb = base[1 * HDIM];
                wc = base[2 * HDIM];
                wd = base[3 * HDIM];
            } else {
                const float* base = w1 + (size_t)j * ZDIM + k4 * 4;
                wa = base[0]; wb = base[1]; wc = base[2]; wd = base[3];
            }
            float acc = h1[j];
            acc = fmaf(xk.x, wa, acc);
            acc = fmaf(xk.y, wb, acc);
            acc = fmaf(xk.z, wc, acc);
            acc = fmaf(xk.w, wd, acc);
            h1[j] = acc;
        }
    }

    #pragma unroll
    for (int j = 0; j < HDIM; ++j) h1[j] = fmaxf(h1[j], 0.0f);

    // ---------- Layers 2+3 fused: m = tanh(h1 @ w2^T + b2) @ w3^T + b3 ----------
    float mr[9];
    #pragma unroll
    for (int r = 0; r < 9; ++r) mr[r] = b3[r];

    #pragma unroll 1
    for (int i = 0; i < HDIM; ++i) {
        const float* w2row = w2 + (size_t)i * HDIM;
        float a0 = 0.f, a1 = 0.f, a2 = 0.f, a3 = 0.f;
        #pragma unroll
        for (int j = 0; j < HDIM; j += 4) {
            a0 = fmaf(w2row[j + 0], h1[j + 0], a0);
            a1 = fmaf(w2row[j + 1], h1[j + 1], a1);
            a2 = fmaf(w2row[j + 2], h1[j + 2], a2);
            a3 = fmaf(w2row[j + 3], h1[j + 3], a3);
        }
        float t = tanhf((a0 + a1) + (a2 + a3) + b2[i]);
        #pragma unroll
        for (int r = 0; r < 9; ++r) {
            float wv = TR ? w3t[i * 9 + r] : w3[r * HDIM + i];
            mr[r] = fmaf(wv, t, mr[r]);
        }
    }

    // ---------- Polar: R = U V^T via scaled Newton (fp64) ----------
    // X <- 0.5 * (g*X + (1/g)*X^{-T});  X^{-T} = cof(X)/det(X)
    // g = (||X^{-1}||_F / ||X||_F)^{1/2}  (Frobenius scaling, Higham)
    // Converges to the orthogonal polar factor = U V^T (reflections preserved).
    double X00 = mr[0], X01 = mr[1], X02 = mr[2];
    double X10 = mr[3], X11 = mr[4], X12 = mr[5];
    double X20 = mr[6], X21 = mr[7], X22 = mr[8];

    #pragma unroll 1
    for (int it = 0; it < 12; ++it) {
        double C00 = X11 * X22 - X12 * X21;
        double C01 = X12 * X20 - X10 * X22;
        double C02 = X10 * X21 - X11 * X20;
        double C10 = X02 * X21 - X01 * X22;
        double C11 = X00 * X22 - X02 * X20;
        double C12 = X01 * X20 - X00 * X21;
        double C20 = X01 * X12 - X02 * X11;
        double C21 = X02 * X10 - X00 * X12;
        double C22 = X00 * X11 - X01 * X10;
        double det = X00 * C00 + X01 * C01 + X02 * C02;
        double adet = fabs(det);
        adet = adet < 1e-300 ? 1e-300 : adet;          // singular-M guard
        double sdet = (det < 0.0) ? -adet : adet;
        double nf2 = X00*X00 + X01*X01 + X02*X02
                   + X10*X10 + X11*X11 + X12*X12
                   + X20*X20 + X21*X21 + X22*X22;
        double nc2 = C00*C00 + C01*C01 + C02*C02
                   + C10*C10 + C11*C11 + C12*C12
                   + C20*C20 + C21*C21 + C22*C22;
        // g = ( (sqrt(nc2)/|det|) / sqrt(nf2) )^{1/2}
        double g = sqrt(sqrt(nc2 / nf2) / adet);
        double a = 0.5 * g;
        double b = 0.5 / (g * sdet);                   // b*C == (1/(2g)) * X^{-T}
        X00 = a * X00 + b * C00;  X01 = a * X01 + b * C01;  X02 = a * X02 + b * C02;
        X10 = a * X10 + b * C10;  X11 = a * X11 + b * C11;  X12 = a * X12 + b * C12;
        X20 = a * X20 + b * C20;  X21 = a * X21 + b * C21;  X22 = a * X22 + b * C22;
    }

    float* o = out + (size_t)tid * 9;
    o[0] = (float)X00; o[1] = (float)X01; o[2] = (float)X02;
    o[3] = (float)X10; o[4] = (float)X11; o[5] = (float)X12;
    o[6] = (float)X20; o[7] = (float)X21; o[8] = (float)X22;
}

extern "C" void kernel_launch(void* const* d_in, const int* in_sizes, int n_in,
                              void* d_out, int out_size, void* d_ws, size_t ws_size,
                              hipStream_t stream) {
    const float* x  = (const float*)d_in[0];
    const float* w1 = (const float*)d_in[1];
    const float* b1 = (const float*)d_in[2];
    const float* w2 = (const float*)d_in[3];
    const float* b2 = (const float*)d_in[4];
    const float* w3 = (const float*)d_in[5];
    const float* b3 = (const float*)d_in[6];
    float* out = (float*)d_out;

    int nB = in_sizes[0] / ZDIM;

    const size_t need = (size_t)(HDIM * ZDIM + HDIM * 9) * sizeof(float);
    float* w1t = (float*)d_ws;
    float* w3t = w1t + HDIM * ZDIM;

    dim3 block(256);
    dim3 grid((nB + 255) / 256);

    if (ws_size >= need) {
        dim3 pgrid((HDIM * ZDIM + 255) / 256);
        prep_transpose<<<pgrid, block, 0, stream>>>(w1, w3, w1t, w3t);
        pose_main<true><<<grid, block, 0, stream>>>(x, w1, b1, w2, b2, w3, b3,
                                                    w1t, w3t, out, nB);
    } else {
        pose_main<false><<<grid, block, 0, stream>>>(x, w1, b1, w2, b2, w3, b3,
                                                     nullptr, nullptr, out, nB);
    }
}

// Round 4
// 213.067 us; speedup vs baseline: 1.1923x; 1.1923x over previous
//
#include <hip/hip_runtime.h>
#include <math.h>

#define ZDIM 128
#define HDIM 100
#define JB   50   // layer-1 j-block: 2 passes, peak live regs ~ h1[100] + x[8] + misc

// Prep: transpose w1 [100][128] -> w1t [128][100] and w3 [9][100] -> w3t [100][9]
// so the main kernel's unrolled j/r loops read CONTIGUOUS wave-uniform rows
// (-> compiler emits s_load_dwordx16 batches on the scalar pipe, parallel to VALU).
__global__ void prep_transpose(const float* __restrict__ w1,
                               const float* __restrict__ w3,
                               float* __restrict__ w1t,
                               float* __restrict__ w3t) {
    int idx = blockIdx.x * blockDim.x + threadIdx.x;
    if (idx < HDIM * ZDIM) {
        int j = idx / ZDIM;          // 0..99
        int k = idx - j * ZDIM;      // 0..127
        w1t[k * HDIM + j] = w1[idx];
    }
    if (idx < 9 * HDIM) {
        int r = idx / HDIM;          // 0..8
        int i = idx - r * HDIM;      // 0..99
        w3t[i * 9 + r] = w3[idx];
    }
}

// Fast tanh: tanh(v) = (e-1)/(e+1), e = exp(2v).
// Safe here: pre-activation |v| <~ 15 << 44 (no overflow); err ~3e-7 abs,
// far below the fp32 noise already in the pipeline.
__device__ __forceinline__ float fast_tanh(float v) {
    float e = __expf(2.0f * v);
#if __has_builtin(__builtin_amdgcn_rcpf)
    float r = __builtin_amdgcn_rcpf(e + 1.0f);
    return (e - 1.0f) * r;
#else
    return (e - 1.0f) / (e + 1.0f);
#endif
}

// One thread = one sample. launch_bounds(256,4): 4 waves/SIMD == exactly what the
// grid supplies (262144/64/256CU/4SIMD = 4) -> VGPR budget 128 is free headroom.
template<bool TR>
__global__ __launch_bounds__(256, 4) void pose_main(
    const float* __restrict__ x,
    const float* __restrict__ w1,   // [100][128]
    const float* __restrict__ b1,   // [100]
    const float* __restrict__ w2,   // [100][100]
    const float* __restrict__ b2,   // [100]
    const float* __restrict__ w3,   // [9][100]
    const float* __restrict__ b3,   // [9]
    const float* __restrict__ w1t,  // [128][100] (TR path)
    const float* __restrict__ w3t,  // [100][9]   (TR path)
    float* __restrict__ out,
    int nB)
{
    int tid = blockIdx.x * blockDim.x + threadIdx.x;
    if (tid >= nB) return;

    const float4* xrow4 = reinterpret_cast<const float4*>(x + (size_t)tid * ZDIM);

    // ---------- Layer 1: h1 = relu(x @ w1^T + b1), j-blocked (2 passes of 50) ----
    // Pass jb re-reads the x row (2nd pass hits L2/L3; x fits in 256MB L3).
    // All weight addresses are wave-uniform -> scalar s_loads, off the VMEM pipe.
    float h1[HDIM];

    #pragma unroll
    for (int jb = 0; jb < HDIM / JB; ++jb) {          // static after unroll
        float acc[JB];
        #pragma unroll
        for (int j = 0; j < JB; ++j) acc[j] = b1[jb * JB + j];

        #pragma unroll 1
        for (int k8 = 0; k8 < ZDIM / 8; ++k8) {
            const float4 xa = xrow4[2 * k8 + 0];
            const float4 xb = xrow4[2 * k8 + 1];
            const float xs[8] = { xa.x, xa.y, xa.z, xa.w,
                                  xb.x, xb.y, xb.z, xb.w };
            #pragma unroll
            for (int kk = 0; kk < 8; ++kk) {
                const int k = k8 * 8 + kk;
                const float xv = xs[kk];
                if (TR) {
                    const float* wrow = w1t + (size_t)k * HDIM + jb * JB;
                    #pragma unroll
                    for (int j = 0; j < JB; ++j)
                        acc[j] = fmaf(xv, wrow[j], acc[j]);
                } else {
                    #pragma unroll
                    for (int j = 0; j < JB; ++j)
                        acc[j] = fmaf(xv, w1[(size_t)(jb * JB + j) * ZDIM + k], acc[j]);
                }
            }
        }
        #pragma unroll
        for (int j = 0; j < JB; ++j) h1[jb * JB + j] = fmaxf(acc[j], 0.0f);
    }

    // ---------- Layers 2+3 fused: m = tanh(h1 @ w2^T + b2) @ w3^T + b3 ----------
    float mr[9];
    #pragma unroll
    for (int r = 0; r < 9; ++r) mr[r] = b3[r];

    #pragma unroll 1
    for (int i = 0; i < HDIM; ++i) {
        const float* w2row = w2 + (size_t)i * HDIM;   // wave-uniform -> s_loads
        float a0 = 0.f, a1 = 0.f, a2 = 0.f, a3 = 0.f;
        #pragma unroll
        for (int j = 0; j < HDIM; j += 4) {
            a0 = fmaf(w2row[j + 0], h1[j + 0], a0);
            a1 = fmaf(w2row[j + 1], h1[j + 1], a1);
            a2 = fmaf(w2row[j + 2], h1[j + 2], a2);
            a3 = fmaf(w2row[j + 3], h1[j + 3], a3);
        }
        float t = fast_tanh((a0 + a1) + (a2 + a3) + b2[i]);
        #pragma unroll
        for (int r = 0; r < 9; ++r) {
            float wv = TR ? w3t[i * 9 + r] : w3[r * HDIM + i];
            mr[r] = fmaf(wv, t, mr[r]);
        }
    }

    // ---------- Polar: R = U V^T via scaled Newton (fp64, 10 iters) ----------
    // X <- 0.5*(g*X + (1/g)*X^{-T});  X^{-T} = cof(X)/det(X)
    // g = (||X^{-1}||_F / ||X||_F)^{1/2}  (Higham Frobenius scaling)
    // Converges to the orthogonal polar factor = U V^T (reflections preserved).
    double X00 = mr[0], X01 = mr[1], X02 = mr[2];
    double X10 = mr[3], X11 = mr[4], X12 = mr[5];
    double X20 = mr[6], X21 = mr[7], X22 = mr[8];

    #pragma unroll 1
    for (int it = 0; it < 10; ++it) {
        double C00 = X11 * X22 - X12 * X21;
        double C01 = X12 * X20 - X10 * X22;
        double C02 = X10 * X21 - X11 * X20;
        double C10 = X02 * X21 - X01 * X22;
        double C11 = X00 * X22 - X02 * X20;
        double C12 = X01 * X20 - X00 * X21;
        double C20 = X01 * X12 - X02 * X11;
        double C21 = X02 * X10 - X00 * X12;
        double C22 = X00 * X11 - X01 * X10;
        double det = X00 * C00 + X01 * C01 + X02 * C02;
        double adet = fabs(det);
        adet = adet < 1e-300 ? 1e-300 : adet;          // singular-M guard
        double sdet = (det < 0.0) ? -adet : adet;
        double nf2 = X00*X00 + X01*X01 + X02*X02
                   + X10*X10 + X11*X11 + X12*X12
                   + X20*X20 + X21*X21 + X22*X22;
        double nc2 = C00*C00 + C01*C01 + C02*C02
                   + C10*C10 + C11*C11 + C12*C12
                   + C20*C20 + C21*C21 + C22*C22;
        double g = sqrt(sqrt(nc2 / nf2) / adet);
        double a = 0.5 * g;
        double b = 0.5 / (g * sdet);                   // b*C == (1/(2g)) * X^{-T}
        X00 = a * X00 + b * C00;  X01 = a * X01 + b * C01;  X02 = a * X02 + b * C02;
        X10 = a * X10 + b * C10;  X11 = a * X11 + b * C11;  X12 = a * X12 + b * C12;
        X20 = a * X20 + b * C20;  X21 = a * X21 + b * C21;  X22 = a * X22 + b * C22;
    }

    float* o = out + (size_t)tid * 9;
    o[0] = (float)X00; o[1] = (float)X01; o[2] = (float)X02;
    o[3] = (float)X10; o[4] = (float)X11; o[5] = (float)X12;
    o[6] = (float)X20; o[7] = (float)X21; o[8] = (float)X22;
}

extern "C" void kernel_launch(void* const* d_in, const int* in_sizes, int n_in,
                              void* d_out, int out_size, void* d_ws, size_t ws_size,
                              hipStream_t stream) {
    const float* x  = (const float*)d_in[0];
    const float* w1 = (const float*)d_in[1];
    const float* b1 = (const float*)d_in[2];
    const float* w2 = (const float*)d_in[3];
    const float* b2 = (const float*)d_in[4];
    const float* w3 = (const float*)d_in[5];
    const float* b3 = (const float*)d_in[6];
    float* out = (float*)d_out;

    int nB = in_sizes[0] / ZDIM;

    const size_t need = (size_t)(HDIM * ZDIM + HDIM * 9) * sizeof(float);
    float* w1t = (float*)d_ws;
    float* w3t = w1t + HDIM * ZDIM;

    dim3 block(256);
    dim3 grid((nB + 255) / 256);

    if (ws_size >= need) {
        dim3 pgrid((HDIM * ZDIM + 255) / 256);
        prep_transpose<<<pgrid, block, 0, stream>>>(w1, w3, w1t, w3t);
        pose_main<true><<<grid, block, 0, stream>>>(x, w1, b1, w2, b2, w3, b3,
                                                    w1t, w3t, out, nB);
    } else {
        pose_main<false><<<grid, block, 0, stream>>>(x, w1, b1, w2, b2, w3, b3,
                                                     nullptr, nullptr, out, nB);
    }
}

// Round 5
// 208.101 us; speedup vs baseline: 1.2208x; 1.0239x over previous
//
#include <hip/hip_runtime.h>
#include <math.h>

#define ZDIM 128
#define HDIM 100

// Prep: transpose w1 [100][128] -> w1t [128][100] and w3 [9][100] -> w3t [100][9]
// so the main kernel's unrolled j/r loops read CONTIGUOUS wave-uniform rows
// (-> scalar s_load batches on the scalar pipe, parallel to VALU).
__global__ void prep_transpose(const float* __restrict__ w1,
                               const float* __restrict__ w3,
                               float* __restrict__ w1t,
                               float* __restrict__ w3t) {
    int idx = blockIdx.x * blockDim.x + threadIdx.x;
    if (idx < HDIM * ZDIM) {
        int j = idx / ZDIM;          // 0..99
        int k = idx - j * ZDIM;      // 0..127
        w1t[k * HDIM + j] = w1[idx];
    }
    if (idx < 9 * HDIM) {
        int r = idx / HDIM;          // 0..8
        int i = idx - r * HDIM;      // 0..99
        w3t[i * 9 + r] = w3[idx];
    }
}

// Fast tanh: tanh(v) = (e-1)/(e+1), e = exp(2v). |v| <~ 15 here -> no overflow;
// err ~3e-7 abs, far below the pipeline's fp32 noise.
__device__ __forceinline__ float fast_tanh(float v) {
    float e = __expf(2.0f * v);
    return (e - 1.0f) / (e + 1.0f);
}

// One thread = one sample, SINGLE pass over x (acc[100] resident in VGPRs).
// Grid supplies exactly 4 waves/SIMD -> launch_bounds(256,4) makes the full
// 128-VGPR budget free. x is double-buffered one k4-iteration ahead so the
// ~900-cycle HBM latency hides under the 400-FMA body.
template<bool TR>
__global__ __launch_bounds__(256, 4) void pose_main(
    const float* __restrict__ x,
    const float* __restrict__ w1,   // [100][128]
    const float* __restrict__ b1,   // [100]
    const float* __restrict__ w2,   // [100][100]
    const float* __restrict__ b2,   // [100]
    const float* __restrict__ w3,   // [9][100]
    const float* __restrict__ b3,   // [9]
    const float* __restrict__ w1t,  // [128][100] (TR path)
    const float* __restrict__ w3t,  // [100][9]   (TR path)
    float* __restrict__ out,
    int nB)
{
    int tid = blockIdx.x * blockDim.x + threadIdx.x;
    if (tid >= nB) return;

    const float4* xrow4 = reinterpret_cast<const float4*>(x + (size_t)tid * ZDIM);

    // ---------- Layer 1: h1 = relu(x @ w1^T + b1), single pass ----------
    float h1[HDIM];
    #pragma unroll
    for (int j = 0; j < HDIM; ++j) h1[j] = b1[j];

    float4 cur = xrow4[0];
    #pragma unroll 1
    for (int k4 = 0; k4 < ZDIM / 4; ++k4) {
        // prefetch next float4 (last iter harmlessly reloads [0], unused)
        float4 nxt = xrow4[(k4 + 1) & (ZDIM / 4 - 1)];
        const float xs[4] = { cur.x, cur.y, cur.z, cur.w };
        #pragma unroll
        for (int kk = 0; kk < 4; ++kk) {
            const int k = k4 * 4 + kk;
            const float xv = xs[kk];
            if (TR) {
                const float* wrow = w1t + (size_t)k * HDIM;   // wave-uniform
                #pragma unroll
                for (int j = 0; j < HDIM; ++j)
                    h1[j] = fmaf(xv, wrow[j], h1[j]);
            } else {
                #pragma unroll
                for (int j = 0; j < HDIM; ++j)
                    h1[j] = fmaf(xv, w1[(size_t)j * ZDIM + k], h1[j]);
            }
        }
        cur = nxt;
    }

    #pragma unroll
    for (int j = 0; j < HDIM; ++j) h1[j] = fmaxf(h1[j], 0.0f);

    // ---------- Layers 2+3 fused: m = tanh(h1 @ w2^T + b2) @ w3^T + b3 ----------
    float mr[9];
    #pragma unroll
    for (int r = 0; r < 9; ++r) mr[r] = b3[r];

    #pragma unroll 2    // two weight-rows in flight for the scalar pipe
    for (int i = 0; i < HDIM; ++i) {
        const float* w2row = w2 + (size_t)i * HDIM;   // wave-uniform -> s_loads
        float a0 = 0.f, a1 = 0.f, a2 = 0.f, a3 = 0.f;
        #pragma unroll
        for (int j = 0; j < HDIM; j += 4) {
            a0 = fmaf(w2row[j + 0], h1[j + 0], a0);
            a1 = fmaf(w2row[j + 1], h1[j + 1], a1);
            a2 = fmaf(w2row[j + 2], h1[j + 2], a2);
            a3 = fmaf(w2row[j + 3], h1[j + 3], a3);
        }
        float t = fast_tanh((a0 + a1) + (a2 + a3) + b2[i]);
        #pragma unroll
        for (int r = 0; r < 9; ++r) {
            float wv = TR ? w3t[i * 9 + r] : w3[r * HDIM + i];
            mr[r] = fmaf(wv, t, mr[r]);
        }
    }

    // ---------- Polar: R = U V^T via scaled Newton (fp64, 10 iters) ----------
    // X <- 0.5*(g*X + (1/g)*X^{-T});  X^{-T} = cof(X)/det(X)
    // g = (||X^{-1}||_F / ||X||_F)^{1/2}  (Higham Frobenius scaling)
    // Converges to the orthogonal polar factor = U V^T (reflections preserved).
    double X00 = mr[0], X01 = mr[1], X02 = mr[2];
    double X10 = mr[3], X11 = mr[4], X12 = mr[5];
    double X20 = mr[6], X21 = mr[7], X22 = mr[8];

    #pragma unroll 1
    for (int it = 0; it < 10; ++it) {
        double C00 = X11 * X22 - X12 * X21;
        double C01 = X12 * X20 - X10 * X22;
        double C02 = X10 * X21 - X11 * X20;
        double C10 = X02 * X21 - X01 * X22;
        double C11 = X00 * X22 - X02 * X20;
        double C12 = X01 * X20 - X00 * X21;
        double C20 = X01 * X12 - X02 * X11;
        double C21 = X02 * X10 - X00 * X12;
        double C22 = X00 * X11 - X01 * X10;
        double det = X00 * C00 + X01 * C01 + X02 * C02;
        double adet = fabs(det);
        adet = adet < 1e-300 ? 1e-300 : adet;          // singular-M guard
        double sdet = (det < 0.0) ? -adet : adet;
        double nf2 = X00*X00 + X01*X01 + X02*X02
                   + X10*X10 + X11*X11 + X12*X12
                   + X20*X20 + X21*X21 + X22*X22;
        double nc2 = C00*C00 + C01*C01 + C02*C02
                   + C10*C10 + C11*C11 + C12*C12
                   + C20*C20 + C21*C21 + C22*C22;
        double g = sqrt(sqrt(nc2 / nf2) / adet);
        double a = 0.5 * g;
        double b = 0.5 / (g * sdet);                   // b*C == (1/(2g)) * X^{-T}
        X00 = a * X00 + b * C00;  X01 = a * X01 + b * C01;  X02 = a * X02 + b * C02;
        X10 = a * X10 + b * C10;  X11 = a * X11 + b * C11;  X12 = a * X12 + b * C12;
        X20 = a * X20 + b * C20;  X21 = a * X21 + b * C21;  X22 = a * X22 + b * C22;
    }

    float* o = out + (size_t)tid * 9;
    o[0] = (float)X00; o[1] = (float)X01; o[2] = (float)X02;
    o[3] = (float)X10; o[4] = (float)X11; o[5] = (float)X12;
    o[6] = (float)X20; o[7] = (float)X21; o[8] = (float)X22;
}

extern "C" void kernel_launch(void* const* d_in, const int* in_sizes, int n_in,
                              void* d_out, int out_size, void* d_ws, size_t ws_size,
                              hipStream_t stream) {
    const float* x  = (const float*)d_in[0];
    const float* w1 = (const float*)d_in[1];
    const float* b1 = (const float*)d_in[2];
    const float* w2 = (const float*)d_in[3];
    const float* b2 = (const float*)d_in[4];
    const float* w3 = (const float*)d_in[5];
    const float* b3 = (const float*)d_in[6];
    float* out = (float*)d_out;

    int nB = in_sizes[0] / ZDIM;

    const size_t need = (size_t)(HDIM * ZDIM + HDIM * 9) * sizeof(float);
    float* w1t = (float*)d_ws;
    float* w3t = w1t + HDIM * ZDIM;

    dim3 block(256);
    dim3 grid((nB + 255) / 256);

    if (ws_size >= need) {
        dim3 pgrid((HDIM * ZDIM + 255) / 256);
        prep_transpose<<<pgrid, block, 0, stream>>>(w1, w3, w1t, w3t);
        pose_main<true><<<grid, block, 0, stream>>>(x, w1, b1, w2, b2, w3, b3,
                                                    w1t, w3t, out, nB);
    } else {
        pose_main<false><<<grid, block, 0, stream>>>(x, w1, b1, w2, b2, w3, b3,
                                                     nullptr, nullptr, out, nB);
    }
}